// Round 1
// baseline (1504.605 us; speedup 1.0000x reference)
//
#include <hip/hip_runtime.h>
#include <hip/hip_bf16.h>

// Problem constants (from reference): x [2, 2048, 768], 12 heads, head_d 64.
#define BD 2
#define SLEN 2048
#define DDIM 768
#define HNUM 12
#define HD 64
#define MROWS (BD * SLEN)   // 4096

// ---------------------------------------------------------------------------
// GEMM body: out = A[M,768] @ W[768,768]^T + bias  (NT gemm, both k-contiguous)
// 128x128 block tile, BK=16, 256 threads, 8x8 register microtile.
// MODE 0: out[m*768 + n] (plain row-major, final projection)
// MODE 1: out scattered to [B, H, S, hd] (QKV head layout)
// ---------------------------------------------------------------------------
template <int MODE>
__device__ __forceinline__ void gemm_body(const float* __restrict__ A,
                                          const float* __restrict__ W,
                                          const float* __restrict__ bias,
                                          float* __restrict__ out) {
  __shared__ float As[16][132];  // [k][m], pad 132 (528B row, 16B-aligned)
  __shared__ float Bs[16][132];  // [k][n]

  const int n0 = blockIdx.x * 128;
  const int m0 = blockIdx.y * 128;
  const int t = threadIdx.x;
  const int tx = t & 15;   // n subtile
  const int ty = t >> 4;   // m subtile

  float acc[8][8];
  #pragma unroll
  for (int i = 0; i < 8; ++i)
    #pragma unroll
    for (int j = 0; j < 8; ++j) acc[i][j] = 0.f;

  // load indices: 512 float4s per tile (128 rows x 4 float4), 2 per thread
  const int row0 = t >> 2;             // 0..63
  const int c40 = (t & 3) * 4;         // k sub-offset in floats
  const int row1 = row0 + 64;

  for (int k0 = 0; k0 < DDIM; k0 += 16) {
    float4 a0 = *(const float4*)(A + (size_t)(m0 + row0) * DDIM + k0 + c40);
    float4 a1 = *(const float4*)(A + (size_t)(m0 + row1) * DDIM + k0 + c40);
    float4 w0 = *(const float4*)(W + (size_t)(n0 + row0) * DDIM + k0 + c40);
    float4 w1 = *(const float4*)(W + (size_t)(n0 + row1) * DDIM + k0 + c40);
    __syncthreads();  // protect previous iteration's readers
    As[c40 + 0][row0] = a0.x; As[c40 + 1][row0] = a0.y;
    As[c40 + 2][row0] = a0.z; As[c40 + 3][row0] = a0.w;
    As[c40 + 0][row1] = a1.x; As[c40 + 1][row1] = a1.y;
    As[c40 + 2][row1] = a1.z; As[c40 + 3][row1] = a1.w;
    Bs[c40 + 0][row0] = w0.x; Bs[c40 + 1][row0] = w0.y;
    Bs[c40 + 2][row0] = w0.z; Bs[c40 + 3][row0] = w0.w;
    Bs[c40 + 0][row1] = w1.x; Bs[c40 + 1][row1] = w1.y;
    Bs[c40 + 2][row1] = w1.z; Bs[c40 + 3][row1] = w1.w;
    __syncthreads();

    #pragma unroll
    for (int k = 0; k < 16; ++k) {
      float ar[8], br[8];
      *(float4*)(ar + 0) = *(const float4*)&As[k][ty * 8 + 0];
      *(float4*)(ar + 4) = *(const float4*)&As[k][ty * 8 + 4];
      *(float4*)(br + 0) = *(const float4*)&Bs[k][tx * 8 + 0];
      *(float4*)(br + 4) = *(const float4*)&Bs[k][tx * 8 + 4];
      #pragma unroll
      for (int i = 0; i < 8; ++i)
        #pragma unroll
        for (int j = 0; j < 8; ++j)
          acc[i][j] = fmaf(ar[i], br[j], acc[i][j]);
    }
  }

  float bv[8];
  #pragma unroll
  for (int j = 0; j < 8; ++j) bv[j] = bias[n0 + tx * 8 + j];

  #pragma unroll
  for (int i = 0; i < 8; ++i) {
    const int m = m0 + ty * 8 + i;
    #pragma unroll
    for (int j4 = 0; j4 < 2; ++j4) {
      const int n = n0 + tx * 8 + j4 * 4;
      float4 o;
      o.x = acc[i][j4 * 4 + 0] + bv[j4 * 4 + 0];
      o.y = acc[i][j4 * 4 + 1] + bv[j4 * 4 + 1];
      o.z = acc[i][j4 * 4 + 2] + bv[j4 * 4 + 2];
      o.w = acc[i][j4 * 4 + 3] + bv[j4 * 4 + 3];
      if (MODE == 0) {
        *(float4*)(out + (size_t)m * DDIM + n) = o;
      } else {
        // m -> (b, s); n -> (h, d). 8-aligned n never crosses a head (hd=64).
        const int b_ = m >> 11, s_ = m & (SLEN - 1);
        const int h_ = n >> 6, d_ = n & (HD - 1);
        *(float4*)(out + (((size_t)(b_ * HNUM + h_) * SLEN + s_) * HD) + d_) = o;
      }
    }
  }
}

__global__ __launch_bounds__(256) void gemm_qkv(
    const float* __restrict__ x,
    const float* __restrict__ Wq, const float* __restrict__ bq,
    const float* __restrict__ Wk, const float* __restrict__ bk,
    const float* __restrict__ Wv, const float* __restrict__ bv,
    float* __restrict__ Qo, float* __restrict__ Ko, float* __restrict__ Vo) {
  const float* W;
  const float* bias;
  float* out;
  if (blockIdx.z == 0)      { W = Wq; bias = bq; out = Qo; }
  else if (blockIdx.z == 1) { W = Wk; bias = bk; out = Ko; }
  else                      { W = Wv; bias = bv; out = Vo; }
  gemm_body<1>(x, W, bias, out);
}

__global__ __launch_bounds__(256) void gemm_out(
    const float* __restrict__ A, const float* __restrict__ W,
    const float* __restrict__ bias, float* __restrict__ out) {
  gemm_body<0>(A, W, bias, out);
}

// ---------------------------------------------------------------------------
// Flash attention fwd, causal. Q/K/V in [B,H,S,hd] fp32. Output -> [B,S,D].
// Block: 256 threads handles one (b,h) x 64-row q-tile.
// Thread t: q-row r = t/4, quarter c = t%4 (owns d in [16c,16c+16) and,
// after the score butterfly, j in [16c,16c+16) of each 64-wide k-tile).
// ---------------------------------------------------------------------------
__global__ __launch_bounds__(256) void flash_fwd(
    const float* __restrict__ Q, const float* __restrict__ K,
    const float* __restrict__ V, float* __restrict__ O) {
  const int qt = blockIdx.x;
  const int bh = blockIdx.y;
  const int b = bh / HNUM, h = bh % HNUM;
  const int t = threadIdx.x;
  const int lane = t & 63;
  const int r = t >> 2;
  const int c = t & 3;
  const int d0 = c * 16;
  const int q0 = qt * 64;

  __shared__ float Kt[64][68];  // +4 pad: rows 272B (16B-aligned float4)
  __shared__ float Vt[64][68];

  float qr[16];
  {
    const float* qb = Q + ((size_t)bh * SLEN + q0 + r) * HD + d0;
    #pragma unroll
    for (int i = 0; i < 4; ++i) {
      float4 v = *(const float4*)(qb + i * 4);
      qr[i * 4 + 0] = v.x * 0.125f;  // 1/sqrt(64)
      qr[i * 4 + 1] = v.y * 0.125f;
      qr[i * 4 + 2] = v.z * 0.125f;
      qr[i * 4 + 3] = v.w * 0.125f;
    }
  }

  float acc[16];
  #pragma unroll
  for (int i = 0; i < 16; ++i) acc[i] = 0.f;
  float m_run = -1e30f, l_run = 0.f;

  const int ntiles = qt + 1;  // causal: only k-tiles <= q-tile
  for (int kt = 0; kt < ntiles; ++kt) {
    __syncthreads();
    // stage K,V tile (64x64 each); 16 consecutive lanes cover one 256B row
    #pragma unroll
    for (int p = 0; p < 4; ++p) {
      const int idx = t + p * 256;
      const int row = idx >> 4;
      const int c4 = (idx & 15) * 4;
      const size_t g = ((size_t)bh * SLEN + (size_t)kt * 64 + row) * HD + c4;
      *(float4*)&Kt[row][c4] = *(const float4*)(K + g);
      *(float4*)&Vt[row][c4] = *(const float4*)(V + g);
    }
    __syncthreads();

    // scores: partial dot over my d-quarter for all 64 j, butterfly over 4 lanes
    float p_[16];
    #pragma unroll
    for (int jc = 0; jc < 4; ++jc) {
      float sp[16];
      #pragma unroll
      for (int jj = 0; jj < 16; ++jj) {
        const float4* kr = (const float4*)&Kt[jc * 16 + jj][d0];
        float4 k0 = kr[0], k1 = kr[1], k2 = kr[2], k3 = kr[3];
        float s = qr[0] * k0.x + qr[1] * k0.y + qr[2] * k0.z + qr[3] * k0.w;
        s = fmaf(qr[4], k1.x, s);  s = fmaf(qr[5], k1.y, s);
        s = fmaf(qr[6], k1.z, s);  s = fmaf(qr[7], k1.w, s);
        s = fmaf(qr[8], k2.x, s);  s = fmaf(qr[9], k2.y, s);
        s = fmaf(qr[10], k2.z, s); s = fmaf(qr[11], k2.w, s);
        s = fmaf(qr[12], k3.x, s); s = fmaf(qr[13], k3.y, s);
        s = fmaf(qr[14], k3.z, s); s = fmaf(qr[15], k3.w, s);
        sp[jj] = s;
      }
      #pragma unroll
      for (int jj = 0; jj < 16; ++jj) {
        float v2 = sp[jj];
        v2 += __shfl_xor(v2, 1);
        v2 += __shfl_xor(v2, 2);
        sp[jj] = v2;
      }
      if (jc == c) {
        #pragma unroll
        for (int jj = 0; jj < 16; ++jj) p_[jj] = sp[jj];
      }
    }

    // causal mask (diagonal tile only): my j slot is d0+jj, my q row is r
    if (kt == qt) {
      #pragma unroll
      for (int jj = 0; jj < 16; ++jj)
        if (d0 + jj > r) p_[jj] = -1e30f;
    }

    // online softmax (state duplicated across the 4 lanes of a row)
    float tm = p_[0];
    #pragma unroll
    for (int jj = 1; jj < 16; ++jj) tm = fmaxf(tm, p_[jj]);
    tm = fmaxf(tm, __shfl_xor(tm, 1));
    tm = fmaxf(tm, __shfl_xor(tm, 2));
    const float m_new = fmaxf(m_run, tm);
    const float resc = __expf(m_run - m_new);
    float ts = 0.f;
    #pragma unroll
    for (int jj = 0; jj < 16; ++jj) {
      p_[jj] = __expf(p_[jj] - m_new);
      ts += p_[jj];
    }
    ts += __shfl_xor(ts, 1);
    ts += __shfl_xor(ts, 2);
    l_run = l_run * resc + ts;
    m_run = m_new;
    #pragma unroll
    for (int i = 0; i < 16; ++i) acc[i] *= resc;

    // PV: rotate P quarters through the 4 lanes of each row
    #pragma unroll
    for (int st = 0; st < 4; ++st) {
      const int jq = (c + st) & 3;
      const int src = (lane & ~3) | jq;
      float pj[16];
      #pragma unroll
      for (int jj = 0; jj < 16; ++jj) pj[jj] = __shfl(p_[jj], src, 64);
      #pragma unroll
      for (int jj = 0; jj < 16; ++jj) {
        const float4* vr = (const float4*)&Vt[jq * 16 + jj][d0];
        float4 v0 = vr[0], v1 = vr[1], v2 = vr[2], v3 = vr[3];
        const float pv = pj[jj];
        acc[0]  = fmaf(pv, v0.x, acc[0]);  acc[1]  = fmaf(pv, v0.y, acc[1]);
        acc[2]  = fmaf(pv, v0.z, acc[2]);  acc[3]  = fmaf(pv, v0.w, acc[3]);
        acc[4]  = fmaf(pv, v1.x, acc[4]);  acc[5]  = fmaf(pv, v1.y, acc[5]);
        acc[6]  = fmaf(pv, v1.z, acc[6]);  acc[7]  = fmaf(pv, v1.w, acc[7]);
        acc[8]  = fmaf(pv, v2.x, acc[8]);  acc[9]  = fmaf(pv, v2.y, acc[9]);
        acc[10] = fmaf(pv, v2.z, acc[10]); acc[11] = fmaf(pv, v2.w, acc[11]);
        acc[12] = fmaf(pv, v3.x, acc[12]); acc[13] = fmaf(pv, v3.y, acc[13]);
        acc[14] = fmaf(pv, v3.z, acc[14]); acc[15] = fmaf(pv, v3.w, acc[15]);
      }
    }
  }

  // epilogue: normalize, write to [B,S,D] so the output GEMM reads row-major
  const float inv = 1.f / l_run;
  float* ob = O + ((size_t)(b * SLEN + q0 + r)) * DDIM + h * HD + d0;
  #pragma unroll
  for (int i = 0; i < 4; ++i) {
    float4 o;
    o.x = acc[i * 4 + 0] * inv;
    o.y = acc[i * 4 + 1] * inv;
    o.z = acc[i * 4 + 2] * inv;
    o.w = acc[i * 4 + 3] * inv;
    *(float4*)(ob + i * 4) = o;
  }
}

// ---------------------------------------------------------------------------
extern "C" void kernel_launch(void* const* d_in, const int* in_sizes, int n_in,
                              void* d_out, int out_size, void* d_ws, size_t ws_size,
                              hipStream_t stream) {
  const float* x  = (const float*)d_in[0];
  const float* Wq = (const float*)d_in[1];
  const float* bq = (const float*)d_in[2];
  const float* Wk = (const float*)d_in[3];
  const float* bk = (const float*)d_in[4];
  const float* Wv = (const float*)d_in[5];
  const float* bv = (const float*)d_in[6];
  const float* Wo = (const float*)d_in[7];
  const float* bo = (const float*)d_in[8];
  float* out = (float*)d_out;

  float* ws = (float*)d_ws;
  const size_t per = (size_t)MROWS * DDIM;  // 3,145,728 floats
  float* Qb = ws;
  float* Kb = ws + per;
  float* Vb = ws + 2 * per;
  float* AO = ws + 3 * per;  // total 50.3 MB

  dim3 blk(256);
  // fused QKV projection: grid (N/128, M/128, 3)
  gemm_qkv<<<dim3(DDIM / 128, MROWS / 128, 3), blk, 0, stream>>>(
      x, Wq, bq, Wk, bk, Wv, bv, Qb, Kb, Vb);
  // causal flash attention: grid (S/64, B*H)
  flash_fwd<<<dim3(SLEN / 64, BD * HNUM), blk, 0, stream>>>(Qb, Kb, Vb, AO);
  // output projection
  gemm_out<<<dim3(DDIM / 128, MROWS / 128), blk, 0, stream>>>(AO, Wo, bo, out);
}

// Round 2
// 455.074 us; speedup vs baseline: 3.3063x; 3.3063x over previous
//
#include <hip/hip_runtime.h>
#include <hip/hip_bf16.h>

// Problem constants (from reference): x [2, 2048, 768], 12 heads, head_d 64.
#define BD 2
#define SLEN 2048
#define DDIM 768
#define HNUM 12
#define HD 64
#define MROWS (BD * SLEN)   // 4096

using short8 = __attribute__((ext_vector_type(8))) short;
using f32x4 = __attribute__((ext_vector_type(4))) float;

__device__ __forceinline__ short f2bf(float f) {
  __hip_bfloat16 h = __float2bfloat16(f);  // RNE
  return *reinterpret_cast<short*>(&h);
}

// ---------------------------------------------------------------------------
// GEMM body: out = A[M,768] @ W[768,768]^T + bias  (NT gemm, both k-contiguous)
// 128x128 block tile, BK=16, 256 threads, 8x8 register microtile. fp32.
// MODE 0: out[m*768 + n] row-major.  MODE 1: out scattered to [B,H,S,hd].
// ---------------------------------------------------------------------------
template <int MODE>
__device__ __forceinline__ void gemm_body(const float* __restrict__ A,
                                          const float* __restrict__ W,
                                          const float* __restrict__ bias,
                                          float* __restrict__ out) {
  __shared__ float As[16][132];
  __shared__ float Bs[16][132];

  const int n0 = blockIdx.x * 128;
  const int m0 = blockIdx.y * 128;
  const int t = threadIdx.x;
  const int tx = t & 15;
  const int ty = t >> 4;

  float acc[8][8];
  #pragma unroll
  for (int i = 0; i < 8; ++i)
    #pragma unroll
    for (int j = 0; j < 8; ++j) acc[i][j] = 0.f;

  const int row0 = t >> 2;
  const int c40 = (t & 3) * 4;
  const int row1 = row0 + 64;

  for (int k0 = 0; k0 < DDIM; k0 += 16) {
    float4 a0 = *(const float4*)(A + (size_t)(m0 + row0) * DDIM + k0 + c40);
    float4 a1 = *(const float4*)(A + (size_t)(m0 + row1) * DDIM + k0 + c40);
    float4 w0 = *(const float4*)(W + (size_t)(n0 + row0) * DDIM + k0 + c40);
    float4 w1 = *(const float4*)(W + (size_t)(n0 + row1) * DDIM + k0 + c40);
    __syncthreads();
    As[c40 + 0][row0] = a0.x; As[c40 + 1][row0] = a0.y;
    As[c40 + 2][row0] = a0.z; As[c40 + 3][row0] = a0.w;
    As[c40 + 0][row1] = a1.x; As[c40 + 1][row1] = a1.y;
    As[c40 + 2][row1] = a1.z; As[c40 + 3][row1] = a1.w;
    Bs[c40 + 0][row0] = w0.x; Bs[c40 + 1][row0] = w0.y;
    Bs[c40 + 2][row0] = w0.z; Bs[c40 + 3][row0] = w0.w;
    Bs[c40 + 0][row1] = w1.x; Bs[c40 + 1][row1] = w1.y;
    Bs[c40 + 2][row1] = w1.z; Bs[c40 + 3][row1] = w1.w;
    __syncthreads();

    #pragma unroll
    for (int k = 0; k < 16; ++k) {
      float ar[8], br[8];
      *(float4*)(ar + 0) = *(const float4*)&As[k][ty * 8 + 0];
      *(float4*)(ar + 4) = *(const float4*)&As[k][ty * 8 + 4];
      *(float4*)(br + 0) = *(const float4*)&Bs[k][tx * 8 + 0];
      *(float4*)(br + 4) = *(const float4*)&Bs[k][tx * 8 + 4];
      #pragma unroll
      for (int i = 0; i < 8; ++i)
        #pragma unroll
        for (int j = 0; j < 8; ++j)
          acc[i][j] = fmaf(ar[i], br[j], acc[i][j]);
    }
  }

  float bv[8];
  #pragma unroll
  for (int j = 0; j < 8; ++j) bv[j] = bias[n0 + tx * 8 + j];

  #pragma unroll
  for (int i = 0; i < 8; ++i) {
    const int m = m0 + ty * 8 + i;
    #pragma unroll
    for (int j4 = 0; j4 < 2; ++j4) {
      const int n = n0 + tx * 8 + j4 * 4;
      float4 o;
      o.x = acc[i][j4 * 4 + 0] + bv[j4 * 4 + 0];
      o.y = acc[i][j4 * 4 + 1] + bv[j4 * 4 + 1];
      o.z = acc[i][j4 * 4 + 2] + bv[j4 * 4 + 2];
      o.w = acc[i][j4 * 4 + 3] + bv[j4 * 4 + 3];
      if (MODE == 0) {
        *(float4*)(out + (size_t)m * DDIM + n) = o;
      } else {
        const int b_ = m >> 11, s_ = m & (SLEN - 1);
        const int h_ = n >> 6, d_ = n & (HD - 1);
        *(float4*)(out + (((size_t)(b_ * HNUM + h_) * SLEN + s_) * HD) + d_) = o;
      }
    }
  }
}

__global__ __launch_bounds__(256) void gemm_qkv(
    const float* __restrict__ x,
    const float* __restrict__ Wq, const float* __restrict__ bq,
    const float* __restrict__ Wk, const float* __restrict__ bk,
    const float* __restrict__ Wv, const float* __restrict__ bv,
    float* __restrict__ Qo, float* __restrict__ Ko, float* __restrict__ Vo) {
  const float* W;
  const float* bias;
  float* out;
  if (blockIdx.z == 0)      { W = Wq; bias = bq; out = Qo; }
  else if (blockIdx.z == 1) { W = Wk; bias = bk; out = Ko; }
  else                      { W = Wv; bias = bv; out = Vo; }
  gemm_body<1>(x, W, bias, out);
}

__global__ __launch_bounds__(256) void gemm_out(
    const float* __restrict__ A, const float* __restrict__ W,
    const float* __restrict__ bias, float* __restrict__ out) {
  gemm_body<0>(A, W, bias, out);
}

// ---------------------------------------------------------------------------
// Flash attention fwd, causal, bf16 MFMA compute / fp32 softmax state.
// Q/K/V in [B,H,S,hd] fp32. Output -> [B,S,D] fp32.
// Block: 256 threads (4 waves), one (b,h) x 64-row q-tile. Wave w owns q-rows
// [16w,16w+16). KV-tile 64 rows.
// MFMA 16x16x32 bf16 mappings (m89/m92 verified):
//   A: row=lane&15, k=8*(lane>>4)+{0..7}(+32c)   B: col=lane&15, same k
//   D: col=lane&15, row=4*(lane>>4)+reg
// ---------------------------------------------------------------------------
__global__ __launch_bounds__(256) void flash_fwd_mfma(
    const float* __restrict__ Q, const float* __restrict__ K,
    const float* __restrict__ V, float* __restrict__ O) {
  const int bh = blockIdx.x;
  const int qt = (int)gridDim.y - 1 - (int)blockIdx.y;  // heavy tiles first
  const int b = bh / HNUM, h = bh % HNUM;
  const int t = threadIdx.x;
  const int w = t >> 6;
  const int l = t & 63;
  const int x = l & 15;    // MFMA "col" lane id
  const int g = l >> 4;    // MFMA k-group / row-group
  const int q0 = qt * 64;

  __shared__ short Klds[64][72];      // [j][d] bf16, row 144B (16B-aligned)
  __shared__ short Vlds[64][72];      // TRANSPOSED: [d][j] bf16
  __shared__ short Plds[4][16][72];   // per-wave P tile [q][j] bf16

  // Q fragments (A operand), pre-scaled by 1/sqrt(64)
  short8 Qf[2];
  {
    const float* qp = Q + ((size_t)bh * SLEN + q0 + 16 * w + x) * HD;
    #pragma unroll
    for (int c = 0; c < 2; ++c) {
      float4 f0 = *(const float4*)(qp + 8 * g + 32 * c);
      float4 f1 = *(const float4*)(qp + 8 * g + 32 * c + 4);
      Qf[c][0] = f2bf(f0.x * 0.125f); Qf[c][1] = f2bf(f0.y * 0.125f);
      Qf[c][2] = f2bf(f0.z * 0.125f); Qf[c][3] = f2bf(f0.w * 0.125f);
      Qf[c][4] = f2bf(f1.x * 0.125f); Qf[c][5] = f2bf(f1.y * 0.125f);
      Qf[c][6] = f2bf(f1.z * 0.125f); Qf[c][7] = f2bf(f1.w * 0.125f);
    }
  }

  f32x4 Oacc[4];
  #pragma unroll
  for (int dc = 0; dc < 4; ++dc) Oacc[dc] = (f32x4){0.f, 0.f, 0.f, 0.f};
  float m_run[4] = {-1e30f, -1e30f, -1e30f, -1e30f};
  float l_run[4] = {0.f, 0.f, 0.f, 0.f};

  for (int kt = 0; kt <= qt; ++kt) {
    __syncthreads();  // protect LDS from previous tile's readers
    // ---- stage K (row-major bf16): thread -> row j=t>>2, 16 d at (t&3)*16
    {
      const int jr = t >> 2;
      const int d0 = (t & 3) * 16;
      const float* kp = K + ((size_t)bh * SLEN + (size_t)kt * 64 + jr) * HD + d0;
      float4 f0 = *(const float4*)(kp + 0);
      float4 f1 = *(const float4*)(kp + 4);
      float4 f2 = *(const float4*)(kp + 8);
      float4 f3 = *(const float4*)(kp + 12);
      short8 p0, p1;
      p0[0] = f2bf(f0.x); p0[1] = f2bf(f0.y); p0[2] = f2bf(f0.z); p0[3] = f2bf(f0.w);
      p0[4] = f2bf(f1.x); p0[5] = f2bf(f1.y); p0[6] = f2bf(f1.z); p0[7] = f2bf(f1.w);
      p1[0] = f2bf(f2.x); p1[1] = f2bf(f2.y); p1[2] = f2bf(f2.z); p1[3] = f2bf(f2.w);
      p1[4] = f2bf(f3.x); p1[5] = f2bf(f3.y); p1[6] = f2bf(f3.z); p1[7] = f2bf(f3.w);
      *(short8*)&Klds[jr][d0] = p0;
      *(short8*)&Klds[jr][d0 + 8] = p1;
    }
    // ---- stage V transposed: thread covers j=(t&15)+16p, d=(t>>4)*4..+3
    {
      const int dv = (t >> 4) * 4;
      #pragma unroll
      for (int p = 0; p < 4; ++p) {
        const int j = (t & 15) + 16 * p;
        const float* vp = V + ((size_t)bh * SLEN + (size_t)kt * 64 + j) * HD + dv;
        float4 f = *(const float4*)vp;
        Vlds[dv + 0][j] = f2bf(f.x);
        Vlds[dv + 1][j] = f2bf(f.y);
        Vlds[dv + 2][j] = f2bf(f.z);
        Vlds[dv + 3][j] = f2bf(f.w);
      }
    }
    __syncthreads();

    // ---- QK^T: S[16q x 64j] per wave, 4 j-chunks x 2 k-chunks
    f32x4 S[4];
    #pragma unroll
    for (int jc = 0; jc < 4; ++jc) {
      short8 Kf0 = *(const short8*)&Klds[x + 16 * jc][8 * g];
      short8 Kf1 = *(const short8*)&Klds[x + 16 * jc][8 * g + 32];
      f32x4 z = (f32x4){0.f, 0.f, 0.f, 0.f};
      z = __builtin_amdgcn_mfma_f32_16x16x32_bf16(Qf[0], Kf0, z, 0, 0, 0);
      S[jc] = __builtin_amdgcn_mfma_f32_16x16x32_bf16(Qf[1], Kf1, z, 0, 0, 0);
    }

    // ---- causal mask on the diagonal tile
    if (kt == qt) {
      #pragma unroll
      for (int jc = 0; jc < 4; ++jc)
        #pragma unroll
        for (int reg = 0; reg < 4; ++reg)
          if (x + 16 * jc > 16 * w + 4 * g + reg) S[jc][reg] = -1e30f;
    }

    // ---- online softmax (fp32). Row q=4g+reg lives in 16 contiguous lanes.
    float resc[4];
    #pragma unroll
    for (int reg = 0; reg < 4; ++reg) {
      float tm = fmaxf(fmaxf(S[0][reg], S[1][reg]), fmaxf(S[2][reg], S[3][reg]));
      tm = fmaxf(tm, __shfl_xor(tm, 1));
      tm = fmaxf(tm, __shfl_xor(tm, 2));
      tm = fmaxf(tm, __shfl_xor(tm, 4));
      tm = fmaxf(tm, __shfl_xor(tm, 8));
      const float mn = fmaxf(m_run[reg], tm);
      resc[reg] = __expf(m_run[reg] - mn);
      m_run[reg] = mn;
    }
    #pragma unroll
    for (int reg = 0; reg < 4; ++reg) {
      float ts = 0.f;
      #pragma unroll
      for (int jc = 0; jc < 4; ++jc) {
        float p = __expf(S[jc][reg] - m_run[reg]);
        S[jc][reg] = p;
        ts += p;
      }
      ts += __shfl_xor(ts, 1);
      ts += __shfl_xor(ts, 2);
      ts += __shfl_xor(ts, 4);
      ts += __shfl_xor(ts, 8);
      l_run[reg] = l_run[reg] * resc[reg] + ts;
    }
    #pragma unroll
    for (int dc = 0; dc < 4; ++dc)
      #pragma unroll
      for (int reg = 0; reg < 4; ++reg) Oacc[dc][reg] *= resc[reg];

    // ---- P -> LDS (bf16) to convert C-layout into A-fragment layout
    #pragma unroll
    for (int jc = 0; jc < 4; ++jc)
      #pragma unroll
      for (int reg = 0; reg < 4; ++reg)
        Plds[w][4 * g + reg][x + 16 * jc] = f2bf(S[jc][reg]);
    __syncthreads();  // lgkm drain + keeps waves aligned

    // ---- PV: O[16q x 64d] += P[16q x 64j] @ V[64j x 64d]
    short8 Pf0 = *(const short8*)&Plds[w][x][8 * g];
    short8 Pf1 = *(const short8*)&Plds[w][x][8 * g + 32];
    #pragma unroll
    for (int dc = 0; dc < 4; ++dc) {
      short8 Vf0 = *(const short8*)&Vlds[x + 16 * dc][8 * g];
      short8 Vf1 = *(const short8*)&Vlds[x + 16 * dc][8 * g + 32];
      Oacc[dc] = __builtin_amdgcn_mfma_f32_16x16x32_bf16(Pf0, Vf0, Oacc[dc], 0, 0, 0);
      Oacc[dc] = __builtin_amdgcn_mfma_f32_16x16x32_bf16(Pf1, Vf1, Oacc[dc], 0, 0, 0);
    }
  }

  // ---- epilogue: normalize, write [B,S,D] (d = x+16dc, q = q0+16w+4g+reg)
  #pragma unroll
  for (int reg = 0; reg < 4; ++reg) {
    const float inv = 1.f / l_run[reg];
    const int qabs = q0 + 16 * w + 4 * g + reg;
    float* ob = O + ((size_t)(b * SLEN + qabs)) * DDIM + h * HD + x;
    #pragma unroll
    for (int dc = 0; dc < 4; ++dc) ob[16 * dc] = Oacc[dc][reg] * inv;
  }
}

// ---------------------------------------------------------------------------
extern "C" void kernel_launch(void* const* d_in, const int* in_sizes, int n_in,
                              void* d_out, int out_size, void* d_ws, size_t ws_size,
                              hipStream_t stream) {
  const float* x  = (const float*)d_in[0];
  const float* Wq = (const float*)d_in[1];
  const float* bq = (const float*)d_in[2];
  const float* Wk = (const float*)d_in[3];
  const float* bk = (const float*)d_in[4];
  const float* Wv = (const float*)d_in[5];
  const float* bv = (const float*)d_in[6];
  const float* Wo = (const float*)d_in[7];
  const float* bo = (const float*)d_in[8];
  float* out = (float*)d_out;

  float* ws = (float*)d_ws;
  const size_t per = (size_t)MROWS * DDIM;
  float* Qb = ws;
  float* Kb = ws + per;
  float* Vb = ws + 2 * per;
  float* AO = ws + 3 * per;

  dim3 blk(256);
  gemm_qkv<<<dim3(DDIM / 128, MROWS / 128, 3), blk, 0, stream>>>(
      x, Wq, bq, Wk, bk, Wv, bv, Qb, Kb, Vb);
  flash_fwd_mfma<<<dim3(BD * HNUM, SLEN / 64), blk, 0, stream>>>(Qb, Kb, Vb, AO);
  gemm_out<<<dim3(DDIM / 128, MROWS / 128), blk, 0, stream>>>(AO, Wo, bo, out);
}

// Round 4
// 261.732 us; speedup vs baseline: 5.7486x; 1.7387x over previous
//
#include <hip/hip_runtime.h>
#include <hip/hip_bf16.h>

// Problem constants: x [2, 2048, 768], 12 heads, head_d 64.
#define BD 2
#define SLEN 2048
#define DDIM 768
#define HNUM 12
#define HD 64
#define MROWS (BD * SLEN)   // 4096

using short4v = __attribute__((ext_vector_type(4))) short;
using short8 = __attribute__((ext_vector_type(8))) short;
using f32x4 = __attribute__((ext_vector_type(4))) float;

__device__ __forceinline__ short f2bf(float f) {
  __hip_bfloat16 h = __float2bfloat16(f);  // RNE
  return *reinterpret_cast<short*>(&h);
}
__device__ __forceinline__ float bf2f(short s) {
  unsigned int u = ((unsigned int)(unsigned short)s) << 16;
  float f;
  __builtin_memcpy(&f, &u, 4);
  return f;
}

// Workspace layout (shorts):
//   [0, P)          x_hi   -- aliased as AO_hi after gemm_qkv3 is done
//   [P, 2P)         x_lo   -- aliased as AO_lo
//   [2P, 2P+8PW)    Wq_hi, Wq_lo, Wk_hi, Wk_lo, Wv_hi, Wv_lo, Wo_hi, Wo_lo
//   [2P+8PW, +P)    Q bf16 [B,H,S,hd]
//   next P          K bf16
//   next P          V bf16
// Total 5P + 8PW shorts = 40.9 MB (< 50.3 MB proven available).
#define P_ELEM ((size_t)MROWS * DDIM)   // 3,145,728
#define PW_ELEM ((size_t)DDIM * DDIM)   // 589,824

// ---------------------------------------------------------------------------
// Split fp32 -> bf16 (hi, lo) pairs: hi = bf16(v), lo = bf16(v - hi).
// z selects segment: 0=x, 1..4 = Wq,Wk,Wv,Wo.
// ---------------------------------------------------------------------------
__global__ __launch_bounds__(256) void cvt_split(
    const float* __restrict__ x, const float* __restrict__ Wq,
    const float* __restrict__ Wk, const float* __restrict__ Wv,
    const float* __restrict__ Wo, short* __restrict__ ws) {
  const float* src;
  short* hi;
  size_t n;
  switch (blockIdx.z) {
    case 0:  src = x;  hi = ws;                             n = P_ELEM;  break;
    case 1:  src = Wq; hi = ws + 2 * P_ELEM;                n = PW_ELEM; break;
    case 2:  src = Wk; hi = ws + 2 * P_ELEM + 2 * PW_ELEM;  n = PW_ELEM; break;
    case 3:  src = Wv; hi = ws + 2 * P_ELEM + 4 * PW_ELEM;  n = PW_ELEM; break;
    default: src = Wo; hi = ws + 2 * P_ELEM + 6 * PW_ELEM;  n = PW_ELEM; break;
  }
  short* lo = hi + n;
  const size_t n4 = n >> 2;
  for (size_t i = (size_t)blockIdx.x * 256 + threadIdx.x; i < n4;
       i += (size_t)gridDim.x * 256) {
    float4 f = ((const float4*)src)[i];
    short4v h, l;
    h[0] = f2bf(f.x); h[1] = f2bf(f.y); h[2] = f2bf(f.z); h[3] = f2bf(f.w);
    l[0] = f2bf(f.x - bf2f(h[0]));
    l[1] = f2bf(f.y - bf2f(h[1]));
    l[2] = f2bf(f.z - bf2f(h[2]));
    l[3] = f2bf(f.w - bf2f(h[3]));
    ((short4v*)hi)[i] = h;
    ((short4v*)lo)[i] = l;
  }
}

// ---------------------------------------------------------------------------
// bf16x3 MFMA GEMM: C = A @ B^T + bias, A [M,768], B [N=768,768], both as
// (hi,lo) bf16 pairs, k-contiguous. C = Ah*Bh + Ah*Bl + Al*Bh (~fp32).
// 128x128 tile, BK=32, 256 threads (4 waves, 2x2), 16x16x32 bf16 MFMA.
// LDS rows padded to 40 shorts (80 B): b128 reads/writes land 8 lanes per
// bank-quad = throughput floor (conflict-free).
// MODE 0: fp32 out[m*768+n].   MODE 1: bf16 out scattered to [B,H,S,hd],
// value = (acc + bias) * scale  (scale folds the 1/sqrt(hd) into Q).
// ---------------------------------------------------------------------------
template <int MODE>
__device__ __forceinline__ void gemm3_body(
    const short* __restrict__ Ah, const short* __restrict__ Al,
    const short* __restrict__ Bh, const short* __restrict__ Bl,
    const float* __restrict__ bias, float scale, void* __restrict__ outp) {
  __shared__ short As[2][128][40];  // [hi/lo][m][k], 80 B rows
  __shared__ short Bs[2][128][40];

  const int n0 = blockIdx.x * 128;
  const int m0 = blockIdx.y * 128;
  const int t = threadIdx.x;
  const int w = t >> 6, l = t & 63;
  const int wm = w >> 1, wn = w & 1;   // wave -> 64x64 quadrant
  const int x = l & 15, g = l >> 4;    // MFMA lane decomposition

  f32x4 acc[4][4];
  #pragma unroll
  for (int i = 0; i < 4; ++i)
    #pragma unroll
    for (int j = 0; j < 4; ++j) acc[i][j] = (f32x4){0.f, 0.f, 0.f, 0.f};

  const int srow = t >> 1;          // staging row 0..127
  const int skc = (t & 1) * 16;     // staging k offset (shorts)

  for (int k0 = 0; k0 < DDIM; k0 += 32) {
    const short* ap = Ah + (size_t)(m0 + srow) * DDIM + k0 + skc;
    const short* alp = Al + (size_t)(m0 + srow) * DDIM + k0 + skc;
    const short* bp = Bh + (size_t)(n0 + srow) * DDIM + k0 + skc;
    const short* blp = Bl + (size_t)(n0 + srow) * DDIM + k0 + skc;
    short8 rah0 = *(const short8*)(ap);
    short8 rah1 = *(const short8*)(ap + 8);
    short8 ral0 = *(const short8*)(alp);
    short8 ral1 = *(const short8*)(alp + 8);
    short8 rbh0 = *(const short8*)(bp);
    short8 rbh1 = *(const short8*)(bp + 8);
    short8 rbl0 = *(const short8*)(blp);
    short8 rbl1 = *(const short8*)(blp + 8);
    __syncthreads();  // protect previous iteration's readers
    *(short8*)&As[0][srow][skc] = rah0;
    *(short8*)&As[0][srow][skc + 8] = rah1;
    *(short8*)&As[1][srow][skc] = ral0;
    *(short8*)&As[1][srow][skc + 8] = ral1;
    *(short8*)&Bs[0][srow][skc] = rbh0;
    *(short8*)&Bs[0][srow][skc + 8] = rbh1;
    *(short8*)&Bs[1][srow][skc] = rbl0;
    *(short8*)&Bs[1][srow][skc + 8] = rbl1;
    __syncthreads();

    short8 af[2][4], bf[2][4];
    #pragma unroll
    for (int i = 0; i < 4; ++i) {
      af[0][i] = *(const short8*)&As[0][wm * 64 + i * 16 + x][8 * g];
      af[1][i] = *(const short8*)&As[1][wm * 64 + i * 16 + x][8 * g];
    }
    #pragma unroll
    for (int j = 0; j < 4; ++j) {
      bf[0][j] = *(const short8*)&Bs[0][wn * 64 + j * 16 + x][8 * g];
      bf[1][j] = *(const short8*)&Bs[1][wn * 64 + j * 16 + x][8 * g];
    }
    #pragma unroll
    for (int i = 0; i < 4; ++i)
      #pragma unroll
      for (int j = 0; j < 4; ++j) {
        acc[i][j] = __builtin_amdgcn_mfma_f32_16x16x32_bf16(af[0][i], bf[0][j], acc[i][j], 0, 0, 0);
        acc[i][j] = __builtin_amdgcn_mfma_f32_16x16x32_bf16(af[0][i], bf[1][j], acc[i][j], 0, 0, 0);
        acc[i][j] = __builtin_amdgcn_mfma_f32_16x16x32_bf16(af[1][i], bf[0][j], acc[i][j], 0, 0, 0);
      }
  }

  // Epilogue. D-layout: col = x (n), row = 4g+reg (m) within each fragment.
  #pragma unroll
  for (int j = 0; j < 4; ++j) {
    const int n = n0 + wn * 64 + j * 16 + x;
    const float bj = bias[n];
    #pragma unroll
    for (int i = 0; i < 4; ++i) {
      #pragma unroll
      for (int reg = 0; reg < 4; ++reg) {
        const int m = m0 + wm * 64 + i * 16 + 4 * g + reg;
        const float v = (acc[i][j][reg] + bj) * scale;
        if (MODE == 0) {
          ((float*)outp)[(size_t)m * DDIM + n] = v;
        } else {
          const int b_ = m >> 11, s_ = m & (SLEN - 1);
          const int h_ = n >> 6, d_ = n & (HD - 1);
          ((short*)outp)[(((size_t)(b_ * HNUM + h_) * SLEN + s_) * HD) + d_] = f2bf(v);
        }
      }
    }
  }
}

__global__ __launch_bounds__(256) void gemm_qkv3(
    const short* __restrict__ ws, const float* __restrict__ bq,
    const float* __restrict__ bk, const float* __restrict__ bv,
    short* __restrict__ Qb, short* __restrict__ Kb, short* __restrict__ Vb) {
  const short* Ah = ws;               // x_hi
  const short* Al = ws + P_ELEM;      // x_lo
  const short* Bh;
  const float* bias;
  short* out;
  float scale;
  switch (blockIdx.z) {
    case 0:  Bh = ws + 2 * P_ELEM;                bias = bq; out = Qb; scale = 0.125f; break;
    case 1:  Bh = ws + 2 * P_ELEM + 2 * PW_ELEM;  bias = bk; out = Kb; scale = 1.f;   break;
    default: Bh = ws + 2 * P_ELEM + 4 * PW_ELEM;  bias = bv; out = Vb; scale = 1.f;   break;
  }
  gemm3_body<1>(Ah, Al, Bh, Bh + PW_ELEM, bias, scale, out);
}

__global__ __launch_bounds__(256) void gemm_out3(
    const short* __restrict__ AOh, const short* __restrict__ AOl,
    const short* __restrict__ Wh, const short* __restrict__ Wl,
    const float* __restrict__ bias, float* __restrict__ out) {
  gemm3_body<0>(AOh, AOl, Wh, Wl, bias, 1.f, out);
}

// ---------------------------------------------------------------------------
// Flash attention fwd, causal, bf16 MFMA / fp32 softmax state.
// Q/K/V bf16 [B,H,S,hd] (Q pre-scaled by 1/8). Output -> bf16 hi/lo [B,S,D].
// 256 threads (4 waves), one (b,h) x 64-row q-tile; KV-tile 64 rows.
// ---------------------------------------------------------------------------
__global__ __launch_bounds__(256) void flash_fwd_mfma(
    const short* __restrict__ Q, const short* __restrict__ K,
    const short* __restrict__ V, short* __restrict__ AOh,
    short* __restrict__ AOl) {
  const int bh = blockIdx.x;
  const int qt = (int)gridDim.y - 1 - (int)blockIdx.y;  // heavy tiles first
  const int b = bh / HNUM, h = bh % HNUM;
  const int t = threadIdx.x;
  const int w = t >> 6;
  const int l = t & 63;
  const int x = l & 15;
  const int g = l >> 4;
  const int q0 = qt * 64;

  __shared__ short Klds[64][72];      // [j][d]
  __shared__ short Vlds[64][72];      // transposed: [d][j]
  __shared__ short Plds[4][16][72];   // per-wave P tile [q][j]

  short8 Qf[2];
  {
    const short* qp = Q + ((size_t)bh * SLEN + q0 + 16 * w + x) * HD;
    Qf[0] = *(const short8*)(qp + 8 * g);
    Qf[1] = *(const short8*)(qp + 8 * g + 32);
  }

  f32x4 Oacc[4];
  #pragma unroll
  for (int dc = 0; dc < 4; ++dc) Oacc[dc] = (f32x4){0.f, 0.f, 0.f, 0.f};
  float m_run[4] = {-1e30f, -1e30f, -1e30f, -1e30f};
  float l_run[4] = {0.f, 0.f, 0.f, 0.f};

  for (int kt = 0; kt <= qt; ++kt) {
    __syncthreads();
    // stage K rows (2 x short8 per thread)
    {
      const int jr = t >> 2;
      const int d0 = (t & 3) * 16;
      const short* kp = K + ((size_t)bh * SLEN + (size_t)kt * 64 + jr) * HD + d0;
      *(short8*)&Klds[jr][d0] = *(const short8*)kp;
      *(short8*)&Klds[jr][d0 + 8] = *(const short8*)(kp + 8);
    }
    // stage V transposed
    {
      const int dv = (t >> 4) * 4;
      #pragma unroll
      for (int p = 0; p < 4; ++p) {
        const int j = (t & 15) + 16 * p;
        const short* vp = V + ((size_t)bh * SLEN + (size_t)kt * 64 + j) * HD + dv;
        short4v f = *(const short4v*)vp;
        Vlds[dv + 0][j] = f[0];
        Vlds[dv + 1][j] = f[1];
        Vlds[dv + 2][j] = f[2];
        Vlds[dv + 3][j] = f[3];
      }
    }
    __syncthreads();

    // QK^T
    f32x4 S[4];
    #pragma unroll
    for (int jc = 0; jc < 4; ++jc) {
      short8 Kf0 = *(const short8*)&Klds[x + 16 * jc][8 * g];
      short8 Kf1 = *(const short8*)&Klds[x + 16 * jc][8 * g + 32];
      f32x4 z = (f32x4){0.f, 0.f, 0.f, 0.f};
      z = __builtin_amdgcn_mfma_f32_16x16x32_bf16(Qf[0], Kf0, z, 0, 0, 0);
      S[jc] = __builtin_amdgcn_mfma_f32_16x16x32_bf16(Qf[1], Kf1, z, 0, 0, 0);
    }

    if (kt == qt) {
      #pragma unroll
      for (int jc = 0; jc < 4; ++jc)
        #pragma unroll
        for (int reg = 0; reg < 4; ++reg)
          if (x + 16 * jc > 16 * w + 4 * g + reg) S[jc][reg] = -1e30f;
    }

    // online softmax
    float resc[4];
    #pragma unroll
    for (int reg = 0; reg < 4; ++reg) {
      float tm = fmaxf(fmaxf(S[0][reg], S[1][reg]), fmaxf(S[2][reg], S[3][reg]));
      tm = fmaxf(tm, __shfl_xor(tm, 1));
      tm = fmaxf(tm, __shfl_xor(tm, 2));
      tm = fmaxf(tm, __shfl_xor(tm, 4));
      tm = fmaxf(tm, __shfl_xor(tm, 8));
      const float mn = fmaxf(m_run[reg], tm);
      resc[reg] = __expf(m_run[reg] - mn);
      m_run[reg] = mn;
    }
    #pragma unroll
    for (int reg = 0; reg < 4; ++reg) {
      float ts = 0.f;
      #pragma unroll
      for (int jc = 0; jc < 4; ++jc) {
        float p = __expf(S[jc][reg] - m_run[reg]);
        S[jc][reg] = p;
        ts += p;
      }
      ts += __shfl_xor(ts, 1);
      ts += __shfl_xor(ts, 2);
      ts += __shfl_xor(ts, 4);
      ts += __shfl_xor(ts, 8);
      l_run[reg] = l_run[reg] * resc[reg] + ts;
    }
    #pragma unroll
    for (int dc = 0; dc < 4; ++dc)
      #pragma unroll
      for (int reg = 0; reg < 4; ++reg) Oacc[dc][reg] *= resc[reg];

    // P -> LDS (C-layout -> A-fragment layout)
    #pragma unroll
    for (int jc = 0; jc < 4; ++jc)
      #pragma unroll
      for (int reg = 0; reg < 4; ++reg)
        Plds[w][4 * g + reg][x + 16 * jc] = f2bf(S[jc][reg]);
    __syncthreads();

    // PV
    short8 Pf0 = *(const short8*)&Plds[w][x][8 * g];
    short8 Pf1 = *(const short8*)&Plds[w][x][8 * g + 32];
    #pragma unroll
    for (int dc = 0; dc < 4; ++dc) {
      short8 Vf0 = *(const short8*)&Vlds[x + 16 * dc][8 * g];
      short8 Vf1 = *(const short8*)&Vlds[x + 16 * dc][8 * g + 32];
      Oacc[dc] = __builtin_amdgcn_mfma_f32_16x16x32_bf16(Pf0, Vf0, Oacc[dc], 0, 0, 0);
      Oacc[dc] = __builtin_amdgcn_mfma_f32_16x16x32_bf16(Pf1, Vf1, Oacc[dc], 0, 0, 0);
    }
  }

  // epilogue: normalize, write bf16 hi/lo [B,S,D]
  #pragma unroll
  for (int reg = 0; reg < 4; ++reg) {
    const float inv = 1.f / l_run[reg];
    const int qabs = q0 + 16 * w + 4 * g + reg;
    const size_t base = ((size_t)(b * SLEN + qabs)) * DDIM + h * HD + x;
    #pragma unroll
    for (int dc = 0; dc < 4; ++dc) {
      const float v = Oacc[dc][reg] * inv;
      const short hh = f2bf(v);
      AOh[base + 16 * dc] = hh;
      AOl[base + 16 * dc] = f2bf(v - bf2f(hh));
    }
  }
}

// ---------------------------------------------------------------------------
extern "C" void kernel_launch(void* const* d_in, const int* in_sizes, int n_in,
                              void* d_out, int out_size, void* d_ws, size_t ws_size,
                              hipStream_t stream) {
  const float* x  = (const float*)d_in[0];
  const float* Wq = (const float*)d_in[1];
  const float* bq = (const float*)d_in[2];
  const float* Wk = (const float*)d_in[3];
  const float* bk = (const float*)d_in[4];
  const float* Wv = (const float*)d_in[5];
  const float* bv = (const float*)d_in[6];
  const float* Wo = (const float*)d_in[7];
  const float* bo = (const float*)d_in[8];
  float* out = (float*)d_out;

  short* S = (short*)d_ws;
  short* AOh = S;                       // aliases x_hi (free after gemm_qkv3)
  short* AOl = S + P_ELEM;              // aliases x_lo
  const short* Wo_h = S + 2 * P_ELEM + 6 * PW_ELEM;
  const short* Wo_l = Wo_h + PW_ELEM;
  short* Qb = S + 2 * P_ELEM + 8 * PW_ELEM;
  short* Kb = Qb + P_ELEM;
  short* Vb = Kb + P_ELEM;

  dim3 blk(256);
  cvt_split<<<dim3(768, 1, 5), blk, 0, stream>>>(x, Wq, Wk, Wv, Wo, S);
  gemm_qkv3<<<dim3(DDIM / 128, MROWS / 128, 3), blk, 0, stream>>>(
      S, bq, bk, bv, Qb, Kb, Vb);
  flash_fwd_mfma<<<dim3(BD * HNUM, SLEN / 64), blk, 0, stream>>>(
      Qb, Kb, Vb, AOh, AOl);
  gemm_out3<<<dim3(DDIM / 128, MROWS / 128), blk, 0, stream>>>(
      AOh, AOl, Wo_h, Wo_l, bo, out);
}

// Round 5
// 222.363 us; speedup vs baseline: 6.7664x; 1.1770x over previous
//
#include <hip/hip_runtime.h>
#include <hip/hip_bf16.h>

// Problem constants: x [2, 2048, 768], 12 heads, head_d 64.
#define BD 2
#define SLEN 2048
#define DDIM 768
#define HNUM 12
#define HD 64
#define MROWS (BD * SLEN)   // 4096

using short4v = __attribute__((ext_vector_type(4))) short;
using short8 = __attribute__((ext_vector_type(8))) short;
using f32x4 = __attribute__((ext_vector_type(4))) float;
using uint4v = __attribute__((ext_vector_type(4))) unsigned int;

__device__ __forceinline__ short f2bf(float f) {
  __hip_bfloat16 h = __float2bfloat16(f);  // RNE
  return *reinterpret_cast<short*>(&h);
}
__device__ __forceinline__ float bf2f(short s) {
  unsigned int u = ((unsigned int)(unsigned short)s) << 16;
  float f;
  __builtin_memcpy(&f, &u, 4);
  return f;
}
__device__ __forceinline__ unsigned pkbf(float a, float b) {
  return (unsigned)(unsigned short)f2bf(a) |
         ((unsigned)(unsigned short)f2bf(b) << 16);
}

// Workspace layout (shorts):
//   [0, P)          x_hi   -- aliased as AO_hi after gemm_qkv3
//   [P, 2P)         x_lo   -- aliased as AO_lo
//   [2P, 2P+8PW)    Wq_hi, Wq_lo, Wk_hi, Wk_lo, Wv_hi, Wv_lo, Wo_hi, Wo_lo
//   [2P+8PW, +3P)   Q, K, V bf16 [B,H,S,hd]
#define P_ELEM ((size_t)MROWS * DDIM)   // 3,145,728
#define PW_ELEM ((size_t)DDIM * DDIM)   // 589,824

// ---------------------------------------------------------------------------
// Split fp32 -> bf16 (hi, lo): hi = bf16(v), lo = bf16(v - hi).
// ---------------------------------------------------------------------------
__global__ __launch_bounds__(256) void cvt_split(
    const float* __restrict__ x, const float* __restrict__ Wq,
    const float* __restrict__ Wk, const float* __restrict__ Wv,
    const float* __restrict__ Wo, short* __restrict__ ws) {
  const float* src;
  short* hi;
  size_t n;
  switch (blockIdx.z) {
    case 0:  src = x;  hi = ws;                             n = P_ELEM;  break;
    case 1:  src = Wq; hi = ws + 2 * P_ELEM;                n = PW_ELEM; break;
    case 2:  src = Wk; hi = ws + 2 * P_ELEM + 2 * PW_ELEM;  n = PW_ELEM; break;
    case 3:  src = Wv; hi = ws + 2 * P_ELEM + 4 * PW_ELEM;  n = PW_ELEM; break;
    default: src = Wo; hi = ws + 2 * P_ELEM + 6 * PW_ELEM;  n = PW_ELEM; break;
  }
  short* lo = hi + n;
  const size_t n4 = n >> 2;
  for (size_t i = (size_t)blockIdx.x * 256 + threadIdx.x; i < n4;
       i += (size_t)gridDim.x * 256) {
    float4 f = ((const float4*)src)[i];
    short4v h, l;
    h[0] = f2bf(f.x); h[1] = f2bf(f.y); h[2] = f2bf(f.z); h[3] = f2bf(f.w);
    l[0] = f2bf(f.x - bf2f(h[0]));
    l[1] = f2bf(f.y - bf2f(h[1]));
    l[2] = f2bf(f.z - bf2f(h[2]));
    l[3] = f2bf(f.w - bf2f(h[3]));
    ((short4v*)hi)[i] = h;
    ((short4v*)lo)[i] = l;
  }
}

// ---------------------------------------------------------------------------
// bf16x3 MFMA GEMM: C = A @ B^T + bias. Template tile BM x BN, BK=32,
// 256 threads (4 waves, 2x2 quadrants). Linear LDS planes [R][32] (no pad):
// staging writes fully contiguous (conflict-free); b128 frag reads balanced
// 8-way (= b128 floor). Register prefetch of next K-step.
// MODE 0: fp32 out[m*768+n].  MODE 1: bf16 out scattered to [B,H,S,hd],
// value = (acc + bias) * scale.
// ---------------------------------------------------------------------------
template <int BM, int BN, int MODE>
__device__ __forceinline__ void gemm3_body(
    const short* __restrict__ Ah, const short* __restrict__ Al,
    const short* __restrict__ Bh, const short* __restrict__ Bl,
    const float* __restrict__ bias, float scale, void* __restrict__ outp) {
  __shared__ short As[2][BM][32];
  __shared__ short Bs[2][BN][32];

  const int n0 = blockIdx.x * BN;
  const int m0 = blockIdx.y * BM;
  const int t = threadIdx.x;
  const int w = t >> 6, l = t & 63;
  const int wm = w >> 1, wn = w & 1;
  const int x = l & 15, g = l >> 4;

  constexpr int NI = BM / 32, NJ = BN / 32;
  constexpr int QA = BM / 64;   // 256-chunk groups per A plane
  constexpr int QB = BN / 64;
  constexpr int PER = 2 * QA + 2 * QB;

  f32x4 acc[NI][NJ];
  #pragma unroll
  for (int i = 0; i < NI; ++i)
    #pragma unroll
    for (int j = 0; j < NJ; ++j) acc[i][j] = (f32x4){0.f, 0.f, 0.f, 0.f};

  short8 rg[PER];
  auto load_chunks = [&](int k0) {
    #pragma unroll
    for (int q = 0; q < PER; ++q) {
      const short* gp;
      int rowbase, local;
      if (q < QA)               { gp = Ah; rowbase = m0; local = q * 256 + t; }
      else if (q < 2 * QA)      { gp = Al; rowbase = m0; local = (q - QA) * 256 + t; }
      else if (q < 2 * QA + QB) { gp = Bh; rowbase = n0; local = (q - 2 * QA) * 256 + t; }
      else                      { gp = Bl; rowbase = n0; local = (q - 2 * QA - QB) * 256 + t; }
      rg[q] = *(const short8*)(gp + (size_t)(rowbase + (local >> 2)) * DDIM +
                               k0 + (local & 3) * 8);
    }
  };

  load_chunks(0);
  for (int k0 = 0; k0 < DDIM; k0 += 32) {
    __syncthreads();  // previous iteration's readers done
    #pragma unroll
    for (int q = 0; q < PER; ++q) {
      short* lp;
      int local;
      if (q < QA)               { lp = &As[0][0][0]; local = q * 256 + t; }
      else if (q < 2 * QA)      { lp = &As[1][0][0]; local = (q - QA) * 256 + t; }
      else if (q < 2 * QA + QB) { lp = &Bs[0][0][0]; local = (q - 2 * QA) * 256 + t; }
      else                      { lp = &Bs[1][0][0]; local = (q - 2 * QA - QB) * 256 + t; }
      *(short8*)(lp + local * 8) = rg[q];
    }
    if (k0 + 32 < DDIM) load_chunks(k0 + 32);  // flies during MFMA
    __syncthreads();

    short8 af[2][NI], bf[2][NJ];
    #pragma unroll
    for (int i = 0; i < NI; ++i) {
      af[0][i] = *(const short8*)&As[0][wm * (BM / 2) + i * 16 + x][8 * g];
      af[1][i] = *(const short8*)&As[1][wm * (BM / 2) + i * 16 + x][8 * g];
    }
    #pragma unroll
    for (int j = 0; j < NJ; ++j) {
      bf[0][j] = *(const short8*)&Bs[0][wn * (BN / 2) + j * 16 + x][8 * g];
      bf[1][j] = *(const short8*)&Bs[1][wn * (BN / 2) + j * 16 + x][8 * g];
    }
    __builtin_amdgcn_s_setprio(1);
    #pragma unroll
    for (int i = 0; i < NI; ++i)
      #pragma unroll
      for (int j = 0; j < NJ; ++j) {
        acc[i][j] = __builtin_amdgcn_mfma_f32_16x16x32_bf16(af[0][i], bf[0][j], acc[i][j], 0, 0, 0);
        acc[i][j] = __builtin_amdgcn_mfma_f32_16x16x32_bf16(af[0][i], bf[1][j], acc[i][j], 0, 0, 0);
        acc[i][j] = __builtin_amdgcn_mfma_f32_16x16x32_bf16(af[1][i], bf[0][j], acc[i][j], 0, 0, 0);
      }
    __builtin_amdgcn_s_setprio(0);
  }

  // Epilogue: D col = x (n), row = 4g+reg (m).
  #pragma unroll
  for (int j = 0; j < NJ; ++j) {
    const int n = n0 + wn * (BN / 2) + j * 16 + x;
    const float bj = bias[n];
    #pragma unroll
    for (int i = 0; i < NI; ++i) {
      #pragma unroll
      for (int reg = 0; reg < 4; ++reg) {
        const int m = m0 + wm * (BM / 2) + i * 16 + 4 * g + reg;
        const float v = (acc[i][j][reg] + bj) * scale;
        if (MODE == 0) {
          ((float*)outp)[(size_t)m * DDIM + n] = v;
        } else {
          const int b_ = m >> 11, s_ = m & (SLEN - 1);
          const int h_ = n >> 6, d_ = n & (HD - 1);
          ((short*)outp)[(((size_t)(b_ * HNUM + h_) * SLEN + s_) * HD) + d_] = f2bf(v);
        }
      }
    }
  }
}

__global__ __launch_bounds__(256) void gemm_qkv3(
    const short* __restrict__ ws, const float* __restrict__ bq,
    const float* __restrict__ bk, const float* __restrict__ bv,
    short* __restrict__ Qb, short* __restrict__ Kb, short* __restrict__ Vb) {
  const short* Ah = ws;
  const short* Al = ws + P_ELEM;
  const short* Bh;
  const float* bias;
  short* out;
  float scale;
  switch (blockIdx.z) {
    case 0:  Bh = ws + 2 * P_ELEM;                bias = bq; out = Qb; scale = 0.125f; break;
    case 1:  Bh = ws + 2 * P_ELEM + 2 * PW_ELEM;  bias = bk; out = Kb; scale = 1.f;   break;
    default: Bh = ws + 2 * P_ELEM + 4 * PW_ELEM;  bias = bv; out = Vb; scale = 1.f;   break;
  }
  gemm3_body<128, 128, 1>(Ah, Al, Bh, Bh + PW_ELEM, bias, scale, out);
}

__global__ __launch_bounds__(256) void gemm_out3(
    const short* __restrict__ AOh, const short* __restrict__ AOl,
    const short* __restrict__ Wh, const short* __restrict__ Wl,
    const float* __restrict__ bias, float* __restrict__ out) {
  gemm3_body<64, 64, 0>(AOh, AOl, Wh, Wl, bias, 1.f, out);
}

// ---------------------------------------------------------------------------
// Flash attention fwd, causal, swapped-operand MFMA (q lane-local).
// Q/K/V bf16 [B,H,S,hd] (Q pre-scaled 1/8). Out: bf16 hi/lo [B,S,D].
// 256 threads (4 waves), q-tile 64 (16 rows/wave), KV-tile 128.
// QK^T: S^T[j][q] = mfma(A=K, B=Q): lane (x,g) holds S[q=x][j=16jt+4g+r].
// Softmax: per-lane 32 values + shfl_xor{16,32} cross-group reduce.
// P -> PV B-frag redistribution fully in-register (shfl_xor 32 + 16).
// PV: O^T[d][q] = mfma(A=V^T, B=P): Oacc[dc][r] = O[q=x][d=16dc+4g+r].
// ---------------------------------------------------------------------------
__global__ __launch_bounds__(256) void flash_fwd_mfma(
    const short* __restrict__ Q, const short* __restrict__ K,
    const short* __restrict__ V, short* __restrict__ AOh,
    short* __restrict__ AOl) {
  const int bh = blockIdx.x;
  const int qt = 31 - (int)blockIdx.y;  // heavy tiles first
  const int b = bh / HNUM, h = bh % HNUM;
  const int t = threadIdx.x;
  const int w = t >> 6, l = t & 63;
  const int x = l & 15, g = l >> 4;
  const int q0 = qt * 64;
  const int qrow = q0 + 16 * w + x;

  __shared__ short Klds[128][72];   // [j][d], pad 72 -> balanced b128 reads
  __shared__ short Vlds[64][138];   // transposed [d][j], pad 138 (see notes)

  // Q B-fragment: col = x -> q = qrow; k = 8g(+32kc)
  short8 Qf[2];
  {
    const short* qp = Q + ((size_t)bh * SLEN + qrow) * HD;
    Qf[0] = *(const short8*)(qp + 8 * g);
    Qf[1] = *(const short8*)(qp + 8 * g + 32);
  }

  f32x4 Oacc[4];
  #pragma unroll
  for (int dc = 0; dc < 4; ++dc) Oacc[dc] = (f32x4){0.f, 0.f, 0.f, 0.f};
  float m_run = -1e30f, l_run = 0.f;

  const int ntiles = qt / 2 + 1;  // 128-wide KV tiles (3% causal overhang)

  // staging regs: K/V 4 chunks each (chunk = 8 shorts, fully coalesced loads)
  short8 krg[4], vrg[4];
  auto load_tile = [&](int kt) {
    const size_t rowb = (size_t)bh * SLEN + (size_t)kt * 128;
    #pragma unroll
    for (int q = 0; q < 4; ++q) {
      const int c = q * 256 + t;
      krg[q] = *(const short8*)(K + (rowb + (c >> 3)) * HD + (c & 7) * 8);
      vrg[q] = *(const short8*)(V + (rowb + (c >> 3)) * HD + (c & 7) * 8);
    }
  };

  load_tile(0);
  for (int kt = 0; kt < ntiles; ++kt) {
    __syncthreads();  // previous tile's readers done
    #pragma unroll
    for (int q = 0; q < 4; ++q) {
      const int c = q * 256 + t;
      *(short8*)&Klds[c >> 3][(c & 7) * 8] = krg[q];
      const int j = c >> 3, d0 = (c & 7) * 8;
      #pragma unroll
      for (int i = 0; i < 8; ++i) Vlds[d0 + i][j] = vrg[q][i];
    }
    if (kt + 1 < ntiles) load_tile(kt + 1);  // flies during compute
    __syncthreads();

    // ---- QK^T (swapped): S[jt][r] at lane (x,g) = S[q=x][j=16jt+4g+r]
    f32x4 S[8];
    __builtin_amdgcn_s_setprio(1);
    #pragma unroll
    for (int jt = 0; jt < 8; ++jt) {
      short8 Kf0 = *(const short8*)&Klds[16 * jt + x][8 * g];
      short8 Kf1 = *(const short8*)&Klds[16 * jt + x][8 * g + 32];
      f32x4 z = (f32x4){0.f, 0.f, 0.f, 0.f};
      z = __builtin_amdgcn_mfma_f32_16x16x32_bf16(Kf0, Qf[0], z, 0, 0, 0);
      S[jt] = __builtin_amdgcn_mfma_f32_16x16x32_bf16(Kf1, Qf[1], z, 0, 0, 0);
    }
    __builtin_amdgcn_s_setprio(0);

    // ---- causal mask (last tile covers the diagonal + overhang)
    if (kt == ntiles - 1) {
      const int jb = kt * 128 + 4 * g;
      #pragma unroll
      for (int jt = 0; jt < 8; ++jt)
        #pragma unroll
        for (int r = 0; r < 4; ++r)
          if (jb + 16 * jt + r > qrow) S[jt][r] = -1e30f;
    }

    // ---- online softmax, row q=x fully lane-local + 2 shuffles
    float tm = -1e30f;
    #pragma unroll
    for (int jt = 0; jt < 8; ++jt)
      #pragma unroll
      for (int r = 0; r < 4; ++r) tm = fmaxf(tm, S[jt][r]);
    tm = fmaxf(tm, __shfl_xor(tm, 16));
    tm = fmaxf(tm, __shfl_xor(tm, 32));
    const float mn = fmaxf(m_run, tm);
    const float resc = __expf(m_run - mn);
    m_run = mn;
    float ts = 0.f;
    #pragma unroll
    for (int jt = 0; jt < 8; ++jt)
      #pragma unroll
      for (int r = 0; r < 4; ++r) {
        const float p = __expf(S[jt][r] - mn);
        S[jt][r] = p;
        ts += p;
      }
    ts += __shfl_xor(ts, 16);
    ts += __shfl_xor(ts, 32);
    l_run = l_run * resc + ts;
    #pragma unroll
    for (int dc = 0; dc < 4; ++dc) Oacc[dc] *= resc;

    // ---- P -> B-fragment redistribution, in-register.
    // Target: lane (x,g), chunk c holds P[q=x][j=32c+8g+i], i=0..7.
    uint4v PA[4];
    const bool hihalf = (g >= 2);
    const bool oddg = (g & 1);
    #pragma unroll
    for (int c = 0; c < 4; ++c) {
      const unsigned e_lo = pkbf(S[2 * c][0], S[2 * c][1]);
      const unsigned e_hi = pkbf(S[2 * c][2], S[2 * c][3]);
      const unsigned o_lo = pkbf(S[2 * c + 1][0], S[2 * c + 1][1]);
      const unsigned o_hi = pkbf(S[2 * c + 1][2], S[2 * c + 1][3]);
      const unsigned xe_lo = (unsigned)__shfl_xor((int)e_lo, 32);
      const unsigned xe_hi = (unsigned)__shfl_xor((int)e_hi, 32);
      const unsigned xo_lo = (unsigned)__shfl_xor((int)o_lo, 32);
      const unsigned xo_hi = (unsigned)__shfl_xor((int)o_hi, 32);
      const unsigned ap_lo = hihalf ? xo_lo : e_lo;
      const unsigned ap_hi = hihalf ? xo_hi : e_hi;
      const unsigned bp_lo = hihalf ? o_lo : xe_lo;
      const unsigned bp_hi = hihalf ? o_hi : xe_hi;
      const unsigned sa_lo = (unsigned)__shfl_xor((int)ap_lo, 16);
      const unsigned sa_hi = (unsigned)__shfl_xor((int)ap_hi, 16);
      const unsigned sb_lo = (unsigned)__shfl_xor((int)bp_lo, 16);
      const unsigned sb_hi = (unsigned)__shfl_xor((int)bp_hi, 16);
      PA[c][0] = oddg ? sb_lo : ap_lo;
      PA[c][1] = oddg ? sb_hi : ap_hi;
      PA[c][2] = oddg ? bp_lo : sa_lo;
      PA[c][3] = oddg ? bp_hi : sa_hi;
    }

    // ---- PV: O^T[d][q] += V^T[d][j] P^T[j][q]
    __builtin_amdgcn_s_setprio(1);
    #pragma unroll
    for (int dc = 0; dc < 4; ++dc) {
      #pragma unroll
      for (int c = 0; c < 4; ++c) {
        short8 Vf = *(const short8*)&Vlds[16 * dc + x][32 * c + 8 * g];
        Oacc[dc] = __builtin_amdgcn_mfma_f32_16x16x32_bf16(
            Vf, *(const short8*)&PA[c], Oacc[dc], 0, 0, 0);
      }
    }
    __builtin_amdgcn_s_setprio(0);
  }

  // ---- epilogue: O[q=qrow][d=16dc+4g+r], packed short4v hi/lo stores
  const float inv = 1.f / l_run;
  const size_t base = ((size_t)(b * SLEN + qrow)) * DDIM + h * HD + 4 * g;
  #pragma unroll
  for (int dc = 0; dc < 4; ++dc) {
    short4v hi4, lo4;
    #pragma unroll
    for (int r = 0; r < 4; ++r) {
      const float v = Oacc[dc][r] * inv;
      const short hh = f2bf(v);
      hi4[r] = hh;
      lo4[r] = f2bf(v - bf2f(hh));
    }
    *(short4v*)(AOh + base + 16 * dc) = hi4;
    *(short4v*)(AOl + base + 16 * dc) = lo4;
  }
}

// ---------------------------------------------------------------------------
extern "C" void kernel_launch(void* const* d_in, const int* in_sizes, int n_in,
                              void* d_out, int out_size, void* d_ws, size_t ws_size,
                              hipStream_t stream) {
  const float* x  = (const float*)d_in[0];
  const float* Wq = (const float*)d_in[1];
  const float* bq = (const float*)d_in[2];
  const float* Wk = (const float*)d_in[3];
  const float* bk = (const float*)d_in[4];
  const float* Wv = (const float*)d_in[5];
  const float* bv = (const float*)d_in[6];
  const float* Wo = (const float*)d_in[7];
  const float* bo = (const float*)d_in[8];
  float* out = (float*)d_out;

  short* S = (short*)d_ws;
  short* AOh = S;                       // aliases x_hi (free after gemm_qkv3)
  short* AOl = S + P_ELEM;              // aliases x_lo
  const short* Wo_h = S + 2 * P_ELEM + 6 * PW_ELEM;
  const short* Wo_l = Wo_h + PW_ELEM;
  short* Qb = S + 2 * P_ELEM + 8 * PW_ELEM;
  short* Kb = Qb + P_ELEM;
  short* Vb = Kb + P_ELEM;

  dim3 blk(256);
  cvt_split<<<dim3(768, 1, 5), blk, 0, stream>>>(x, Wq, Wk, Wv, Wo, S);
  gemm_qkv3<<<dim3(DDIM / 128, MROWS / 128, 3), blk, 0, stream>>>(
      S, bq, bk, bv, Qb, Kb, Vb);
  flash_fwd_mfma<<<dim3(BD * HNUM, SLEN / 64), blk, 0, stream>>>(
      Qb, Kb, Vb, AOh, AOl);
  gemm_out3<<<dim3(DDIM / 64, MROWS / 64), blk, 0, stream>>>(
      AOh, AOl, Wo_h, Wo_l, bo, out);
}